// Round 10
// baseline (222.638 us; speedup 1.0000x reference)
//
#include <hip/hip_runtime.h>
#include <hip/hip_bf16.h>

// KroneckerProjection: out = X @ kron(A,B), factored.
//   Step 1 (fp32 VALU, verified): T[m][j][k] = sum_i x[m][i*16+k]*A[i][j]
//   Step 2 (bf16 MFMA, verified):  out[m][j*512+l] = sum_k T[m][j][k]*B[k][l]
// r10 = r9 resubmitted (r9's bench died on an unresponsive container; the
// experiment never ran). r9 = r6 MINUS the LDS D-transpose: MFMA D fragments
// stored DIRECTLY with nontemporal dword stores (4 x 64B segments per instr,
// no RFO with nt, HBM3E 64B atom => full-efficiency partial-line writes).
// Removes 512 ds_write + 128 ds_read_b128 + lgkmcnt waits per wave from the
// store phase. Single-variable A/B vs r6 (126.7us).

#define DIN   2048
#define DOUT  8192
#define TS    268      // T_lds row stride (dwords): 16B-aligned, bank-spread

typedef __attribute__((ext_vector_type(8))) short bf16x8;
typedef __attribute__((ext_vector_type(4))) float f32x4;

__device__ __forceinline__ short f2bf(float f) {
    __hip_bfloat16 h = __float2bfloat16(f);   // RNE
    short s;
    __builtin_memcpy(&s, &h, 2);
    return s;
}

__global__ __launch_bounds__(256, 3)
void kron_mfma6_kernel(const float* __restrict__ x,
                       const float* __restrict__ A,
                       const float* __restrict__ B,
                       float* __restrict__ out)
{
    __shared__ __align__(16) float T_lds[16 * TS];        // 17.2 KiB total LDS

    const int t    = threadIdx.x;
    const int w    = t >> 6;                  // wave 0..3
    const int lane = t & 63;
    const int row0 = blockIdx.x * 16;

    // ---- Step 1: rows row0+4w..+3, lane=(r,k) — verified fp32 path
    const int r = lane >> 4, k = lane & 15;
    {
        float T[16];
#pragma unroll
        for (int j = 0; j < 16; ++j) T[j] = 0.f;

        const float* xr = x + (size_t)(row0 + 4 * w + r) * DIN + k;
#pragma unroll 8
        for (int i = 0; i < 128; ++i) {
            const float xv = xr[i * 16];      // coalesced 64B segments
            const float* Ar = A + i * 16;     // uniform -> s_load
#pragma unroll
            for (int j = 0; j < 16; ++j) T[j] = fmaf(xv, Ar[j], T[j]);
        }
        float* Tm = T_lds + (4 * w + r) * TS + k;
#pragma unroll
        for (int j = 0; j < 16; ++j) Tm[j * 16] = T[j];
    }

    // ---- B-frags (verified): elem e = B[k=q*8+e][w*128 + c*16 + n]; q>=2 zero
    const int q = lane >> 4;
    const int n = lane & 15;
    bf16x8 bfrag[8];
#pragma unroll
    for (int c = 0; c < 8; ++c) {
        bf16x8 f = (bf16x8)0;
        if (q < 2) {
            const float* Bp = B + (size_t)(q * 8) * 512 + w * 128 + c * 16 + n;
#pragma unroll
            for (int e = 0; e < 8; ++e) f[e] = f2bf(Bp[(size_t)e * 512]);
        }
        bfrag[c] = f;
    }

    __syncthreads();   // all T rows visible to all waves

    // ---- Step 2: per j, afrag on demand; D stored directly (NT dwords)
    // D layout (verified): D[reg p] = out[row=q*4+p][col=c*16+n]
    float* ob0 = out + (size_t)(row0 + q * 4) * DOUT + w * 128 + n;
#pragma unroll 2
    for (int j = 0; j < 16; ++j) {
        bf16x8 af = (bf16x8)0;
        if (q < 2) {
            const float* Tp = T_lds + n * TS + j * 16 + q * 8;
            float4 t0 = *(const float4*)(Tp);
            float4 t1 = *(const float4*)(Tp + 4);
            af[0] = f2bf(t0.x); af[1] = f2bf(t0.y);
            af[2] = f2bf(t0.z); af[3] = f2bf(t0.w);
            af[4] = f2bf(t1.x); af[5] = f2bf(t1.y);
            af[6] = f2bf(t1.z); af[7] = f2bf(t1.w);
        }

        float* oj = ob0 + j * 512;
#pragma unroll
        for (int c = 0; c < 8; ++c) {
            f32x4 d = {0.f, 0.f, 0.f, 0.f};
            d = __builtin_amdgcn_mfma_f32_16x16x32_bf16(af, bfrag[c], d, 0, 0, 0);
            float* oc = oj + c * 16;
            __builtin_nontemporal_store(d[0], oc);
            __builtin_nontemporal_store(d[1], oc + (size_t)DOUT);
            __builtin_nontemporal_store(d[2], oc + (size_t)2 * DOUT);
            __builtin_nontemporal_store(d[3], oc + (size_t)3 * DOUT);
        }
    }
}

extern "C" void kernel_launch(void* const* d_in, const int* in_sizes, int n_in,
                              void* d_out, int out_size, void* d_ws, size_t ws_size,
                              hipStream_t stream) {
    const float* x = (const float*)d_in[0];
    const float* A = (const float*)d_in[1];
    const float* B = (const float*)d_in[2];
    float* out = (float*)d_out;

    const int nrows = in_sizes[0] / DIN;      // 16384
    const int grid  = nrows / 16;             // 1024 blocks, 16 rows each

    kron_mfma6_kernel<<<dim3(grid), dim3(256), 0, stream>>>(x, A, B, out);
}

// Round 14
// 127.953 us; speedup vs baseline: 1.7400x; 1.7400x over previous
//
#include <hip/hip_runtime.h>
#include <hip/hip_bf16.h>

// KroneckerProjection: out = X @ kron(A,B), factored.
//   Step 1 (fp32 VALU, verified): T[m][j][k] = sum_i x[m][i*16+k]*A[i][j]
//   Step 2 (bf16 MFMA, verified):  out[m][j*512+l] = sum_k T[m][j][k]*B[k][l]
// r14 = r6 champion VERBATIM (126.7us, absmax 2.0). The phase-split
// experiment (r11-r13) died 3x on an unresponsive container; reverting to the
// verified best per pre-commitment. Structure: per-block 16 rows, 4 waves;
// step-1 fp32 in registers -> padded T_lds; bf16 MFMA (K=16 zero-padded in
// 16x16x32); D transposed through per-wave LDS tile; 512B-contiguous
// NONTEMPORAL float4 stores (write-around: the proven +15us lever).

#define DIN   2048
#define DOUT  8192
#define TS    268      // T_lds row stride (dwords): 16B-aligned, bank-spread
#define TRS   132      // transpose tile row stride (dwords): 16B-aligned

typedef __attribute__((ext_vector_type(8))) short bf16x8;
typedef __attribute__((ext_vector_type(4))) float f32x4;

__device__ __forceinline__ short f2bf(float f) {
    __hip_bfloat16 h = __float2bfloat16(f);   // RNE
    short s;
    __builtin_memcpy(&s, &h, 2);
    return s;
}

__global__ __launch_bounds__(256, 3)
void kron_mfma3_kernel(const float* __restrict__ x,
                       const float* __restrict__ A,
                       const float* __restrict__ B,
                       float* __restrict__ out)
{
    __shared__ __align__(16) float T_lds[16 * TS];        // 17.2 KiB
    __shared__ __align__(16) float trans[4][16 * TRS];    // 33.8 KiB

    const int t    = threadIdx.x;
    const int w    = t >> 6;                  // wave 0..3
    const int lane = t & 63;
    const int row0 = blockIdx.x * 16;

    // ---- Step 1: rows row0+4w..+3, lane=(r,k) — verified fp32 path
    const int r = lane >> 4, k = lane & 15;
    {
        float T[16];
#pragma unroll
        for (int j = 0; j < 16; ++j) T[j] = 0.f;

        const float* xr = x + (size_t)(row0 + 4 * w + r) * DIN + k;
#pragma unroll 8
        for (int i = 0; i < 128; ++i) {
            const float xv = xr[i * 16];      // coalesced 64B segments
            const float* Ar = A + i * 16;     // uniform -> s_load
#pragma unroll
            for (int j = 0; j < 16; ++j) T[j] = fmaf(xv, Ar[j], T[j]);
        }
        float* Tm = T_lds + (4 * w + r) * TS + k;
#pragma unroll
        for (int j = 0; j < 16; ++j) Tm[j * 16] = T[j];
    }

    // ---- B-frags (verified): elem e = B[k=q*8+e][w*128 + c*16 + n]; q>=2 zero
    const int q = lane >> 4;
    const int n = lane & 15;
    bf16x8 bfrag[8];
#pragma unroll
    for (int c = 0; c < 8; ++c) {
        bf16x8 f = (bf16x8)0;
        if (q < 2) {
            const float* Bp = B + (size_t)(q * 8) * 512 + w * 128 + c * 16 + n;
#pragma unroll
            for (int e = 0; e < 8; ++e) f[e] = f2bf(Bp[(size_t)e * 512]);
        }
        bfrag[c] = f;
    }

    __syncthreads();   // all T rows visible to all waves

    float* tw = trans[w];

    // ---- Step 2 main loop over j
#pragma unroll 2
    for (int j = 0; j < 16; ++j) {
        // afrag on demand (verified layout): elem e = U[m=n][k=q*8+e]; q>=2 zero
        bf16x8 af = (bf16x8)0;
        if (q < 2) {
            const float* Tp = T_lds + n * TS + j * 16 + q * 8;
            float4 t0 = *(const float4*)(Tp);
            float4 t1 = *(const float4*)(Tp + 4);
            af[0] = f2bf(t0.x); af[1] = f2bf(t0.y);
            af[2] = f2bf(t0.z); af[3] = f2bf(t0.w);
            af[4] = f2bf(t1.x); af[5] = f2bf(t1.y);
            af[6] = f2bf(t1.z); af[7] = f2bf(t1.w);
        }

        // MFMA per 16-col chunk; D(lane(q,n), reg p) = out[row=q*4+p][col=c*16+n]
        // -> write transposed into LDS tile (2-way write banks = free)
#pragma unroll
        for (int c = 0; c < 8; ++c) {
            f32x4 d = {0.f, 0.f, 0.f, 0.f};
            d = __builtin_amdgcn_mfma_f32_16x16x32_bf16(af, bfrag[c], d, 0, 0, 0);
            float* tp = tw + c * 16 + n;
            tp[(q * 4 + 0) * TRS] = d[0];
            tp[(q * 4 + 1) * TRS] = d[1];
            tp[(q * 4 + 2) * TRS] = d[2];
            tp[(q * 4 + 3) * TRS] = d[3];
        }

        // read back coalesced; NONTEMPORAL stores: 512B contiguous per instr
        const int rrow = (lane >> 5);         // 0/1: row within pair
        const int c4   = (lane & 31) * 4;     // col offset within 128-col chunk
        float* ob = out + (size_t)row0 * DOUT + j * 512 + w * 128 + c4;
#pragma unroll
        for (int rp = 0; rp < 8; ++rp) {
            const int row = 2 * rp + rrow;
            f32x4 v = *(const f32x4*)(tw + row * TRS + c4);
            __builtin_nontemporal_store(v, (f32x4*)(ob + (size_t)row * DOUT));
        }
    }
}

extern "C" void kernel_launch(void* const* d_in, const int* in_sizes, int n_in,
                              void* d_out, int out_size, void* d_ws, size_t ws_size,
                              hipStream_t stream) {
    const float* x = (const float*)d_in[0];
    const float* A = (const float*)d_in[1];
    const float* B = (const float*)d_in[2];
    float* out = (float*)d_out;

    const int nrows = in_sizes[0] / DIN;      // 16384
    const int grid  = nrows / 16;             // 1024 blocks, 16 rows each

    kron_mfma3_kernel<<<dim3(grid), dim3(256), 0, stream>>>(x, A, B, out);
}